// Round 1
// baseline (2177.516 us; speedup 1.0000x reference)
//
#include <hip/hip_runtime.h>

// Problem constants
#define ICn 128
#define OCn 256
#define ISn 48
#define OSn 24

// Output tile per block: 4 (d) x 4 (h) x 8 (w) points, 128 output channels
#define TD 4
#define TH 4
#define TW 8

// x tile dims: 2*T + 5
#define XD 13
#define XH 13
#define XW 21
// intermediate widths after separable passes
#define YW 17   // 2*TW+1
#define YD 9    // 2*TD+1
#define YH 9    // 2*TH+1

// LDS layout (floats)
#define XS_LEN (XD*XH*XW)            // 3549 (y tile 9*9*17=1377 aliases here)
#define AS_OFF XS_LEN                // 3549
#define AS_LEN (XD*XH*YW)            // 2873
#define BS_OFF (AS_OFF + AS_LEN)     // 6422
#define BS_LEN (XD*YH*YW)            // 1989
#define WS_OFF 8412                  // 6422+1989=8411, padded to mult of 4 for 16B-aligned rows
#define WROW 136                     // 128 oc + 8 pad (rows stay 16B aligned, write conflicts ~4-way max)
#define LDS_TOT (WS_OFF + 27*WROW)   // 12084 floats = 48336 B

__global__ __launch_bounds__(256) void conv_down3d_fused(
    const float* __restrict__ x, const float* __restrict__ w,
    const float* __restrict__ bias, float* __restrict__ out)
{
    __shared__ float lds[LDS_TOT];
    float* xs = lds;            // x tile; later aliased as y tile
    float* as = lds + AS_OFF;   // after w-axis FIR
    float* bs = lds + BS_OFF;   // after h-axis FIR
    float* ws = lds + WS_OFF;   // weights [tap][oc], row stride WROW
    float* ys = lds;            // y tile (aliases xs; xs dead after pass A)

    const int tid = threadIdx.x;
    int s = blockIdx.x;
    const int tw = s % 3; s /= 3;
    const int th = s % 6; const int td = s / 6;
    const int od0 = td*TD, oh0 = th*TH, ow0 = tw*TW;
    const int oc0 = blockIdx.y * 128;
    const int n   = blockIdx.z;

    // conv-phase mapping: 16 oc-groups x 16 point-groups
    const int og = tid >> 4;         // 0..15 -> 8 ocs each
    const int pg = tid & 15;         // 0..15 -> (od,oh), 8 ow's each
    const int od = pg >> 2;          // 0..3
    const int oh = pg & 3;           // 0..3

    const float kn0 = 1.0f/11.0f, kn1 = 3.0f/11.0f;  // taps {kn0,kn1,kn1,kn1,kn0}

    float acc[8][8];                 // [oc][point(ow)]
    #pragma unroll
    for (int o = 0; o < 8; ++o) {
        const float bv = bias[oc0 + og*8 + o];
        #pragma unroll
        for (int p = 0; p < 8; ++p) acc[o][p] = bv;
    }

    const int x0d = 2*od0 - 3, x0h = 2*oh0 - 3, x0w = 2*ow0 - 3;
    const float* xn = x + (size_t)n * ICn * (ISn*ISn*ISn);
    const float* wg = w + (size_t)oc0 * (ICn*27);

    for (int ic = 0; ic < ICn; ++ic) {
        // ---- stage x tile (zero-pad out-of-range) ----
        const float* xin = xn + (size_t)ic * (ISn*ISn*ISn);
        for (int idx = tid; idx < XS_LEN; idx += 256) {
            int lz = idx / (XH*XW);
            int r  = idx - lz*(XH*XW);
            int ly = r / XW;
            int lx = r - ly*XW;
            int gz = x0d + lz, gy = x0h + ly, gx = x0w + lx;
            float v = 0.0f;
            if ((unsigned)gz < (unsigned)ISn && (unsigned)gy < (unsigned)ISn &&
                (unsigned)gx < (unsigned)ISn)
                v = xin[((size_t)gz*ISn + gy)*ISn + gx];
            xs[idx] = v;
        }
        // ---- stage weights: ws[tap*WROW + oc] <- w[oc0+oc][ic][tap] ----
        for (int idx = tid; idx < 27*128; idx += 256) {
            int oc  = idx / 27;
            int tap = idx - oc*27;
            ws[tap*WROW + oc] = wg[(size_t)oc*(ICn*27) + ic*27 + tap];
        }
        __syncthreads();

        // ---- FIR pass A: along w  (13,13,21)->(13,13,17) ----
        for (int idx = tid; idx < AS_LEN; idx += 256) {
            int z = idx / (XH*YW);
            int r = idx - z*(XH*YW);
            int yy = r / YW;
            int u  = r - yy*YW;
            const float* p0 = &xs[(z*XH + yy)*XW + u];
            as[idx] = kn0*(p0[0] + p0[4]) + kn1*(p0[1] + p0[2] + p0[3]);
        }
        __syncthreads();
        // ---- FIR pass B: along h  (13,13,17)->(13,9,17) ----
        for (int idx = tid; idx < BS_LEN; idx += 256) {
            int z = idx / (YH*YW);
            int r = idx - z*(YH*YW);
            int v = r / YW;
            int u = r - v*YW;
            const float* p0 = &as[(z*XH + v)*YW + u];
            bs[idx] = kn0*(p0[0] + p0[4*YW]) + kn1*(p0[YW] + p0[2*YW] + p0[3*YW]);
        }
        __syncthreads();
        // ---- FIR pass C: along d  (13,9,17)->(9,9,17), writes over xs ----
        for (int idx = tid; idx < YD*YH*YW; idx += 256) {
            int t = idx / (YH*YW);
            int r = idx - t*(YH*YW);
            int v = r / YW;
            int u = r - v*YW;
            const float* p0 = &bs[(t*YH + v)*YW + u];
            ys[idx] = kn0*(p0[0] + p0[4*(YH*YW)]) +
                      kn1*(p0[YH*YW] + p0[2*(YH*YW)] + p0[3*(YH*YW)]);
        }
        __syncthreads();

        // ---- conv accumulate: 8x8 register outer product per thread ----
        #pragma unroll
        for (int a = 0; a < 3; ++a) {
            #pragma unroll
            for (int b = 0; b < 3; ++b) {
                const float* yrow = &ys[((2*od + a)*YH + (2*oh + b))*YW];
                #pragma unroll
                for (int c = 0; c < 3; ++c) {
                    float yv[8];
                    #pragma unroll
                    for (int p = 0; p < 8; ++p) yv[p] = yrow[2*p + c];
                    const float* wrow = &ws[(a*9 + b*3 + c)*WROW + og*8];
                    float wv[8];
                    #pragma unroll
                    for (int o = 0; o < 8; ++o) wv[o] = wrow[o];
                    #pragma unroll
                    for (int o = 0; o < 8; ++o)
                        #pragma unroll
                        for (int p = 0; p < 8; ++p)
                            acc[o][p] += wv[o] * yv[p];
                }
            }
        }
        __syncthreads();
    }

    // ---- epilogue: coalesced float4 stores ----
    #pragma unroll
    for (int o = 0; o < 8; ++o) {
        size_t base = ((((size_t)n*OCn + oc0 + og*8 + o)*OSn + (od0+od))*OSn + (oh0+oh))*OSn + ow0;
        float4 v0 = make_float4(acc[o][0], acc[o][1], acc[o][2], acc[o][3]);
        float4 v1 = make_float4(acc[o][4], acc[o][5], acc[o][6], acc[o][7]);
        *(float4*)(out + base)     = v0;
        *(float4*)(out + base + 4) = v1;
    }
}

extern "C" void kernel_launch(void* const* d_in, const int* in_sizes, int n_in,
                              void* d_out, int out_size, void* d_ws, size_t ws_size,
                              hipStream_t stream) {
    const float* x    = (const float*)d_in[0];
    const float* w    = (const float*)d_in[1];
    const float* bias = (const float*)d_in[2];
    float* out        = (float*)d_out;

    dim3 grid(6*6*3, OCn/128, 2);   // 108 spatial tiles x 2 oc-groups x 2 batch
    dim3 block(256);
    hipLaunchKernelGGL(conv_down3d_fused, grid, block, 0, stream, x, w, bias, out);
}

// Round 2
// 709.079 us; speedup vs baseline: 3.0709x; 3.0709x over previous
//
#include <hip/hip_runtime.h>

// ---------------- problem constants ----------------
#define ICn 128
#define OCn 256
#define ISn 48      // x spatial
#define YSn 49      // y (FIR out) spatial
#define OSn 24      // out spatial
#define YV  117649  // 49^3
#define K0f (1.0f/11.0f)
#define K1f (3.0f/11.0f)

typedef short  short8  __attribute__((ext_vector_type(8)));
typedef short  short4v __attribute__((ext_vector_type(4)));
typedef float  floatx4 __attribute__((ext_vector_type(4)));

static __device__ __forceinline__ unsigned short f2bf(float f) {
    union { float f; unsigned u; } v; v.f = f;
    unsigned r = (v.u + 0x7FFF + ((v.u >> 16) & 1)) >> 16;   // RNE
    return (unsigned short)r;
}

// ============================================================
// Kernel 0: repack w (fp32, [256][128][3][3][3]) -> bf16 wt in d_ws
// layout: wt[g=2][tap=27][chunk=4][oc=128][ic=32]
// ============================================================
#define WT_ELEMS (2*27*4*128*32)   // 884736
__global__ void w_pack(const float* __restrict__ w, unsigned short* __restrict__ wt) {
    int idx = blockIdx.x * 256 + threadIdx.x;
    const int stride = 864 * 256;
    for (; idx < WT_ELEMS; idx += stride) {
        int i  = idx & 31;
        int o  = (idx >> 5) & 127;
        int ch = (idx >> 12) & 3;
        int rest = idx >> 14;          // g*27 + t
        int t  = rest % 27;
        int g  = rest / 27;
        float v = w[(((size_t)(g*128 + o) * 128) + (ch*32 + i)) * 27 + t];
        wt[idx] = f2bf(v);
    }
}

// ============================================================
// Kernel 1: separable FIR  x(2,128,48^3) fp32 -> y(2,49^3,128) bf16
// y layout: [n][z*2401+y*49+x][ic]  (ic innermost, 256B rows)
// tile: 7x7x7 y-points, 32-ic group; grid (343, 4, 2)
// ============================================================
__global__ __launch_bounds__(256, 3) void fir_y_bf16(
    const float* __restrict__ x, unsigned short* __restrict__ yb)
{
    __shared__ float xs[2*11*11*12];          // x tile, row pad 11->12
    __shared__ float as_[2*11*11*8];          // after W-pass, row pad 7->8
    __shared__ float bs_[2*11*7*8];           // after H-pass
    __shared__ unsigned short ysl[32*343];    // [ic_local][sp] (transposed for conflict-free writes)

    const int tid = threadIdx.x;
    int bx = blockIdx.x;
    const int tz = bx / 49; int r0 = bx - tz*49;
    const int ty = r0 / 7;  const int tx = r0 - ty*7;
    const int z0 = tz*7, y0 = ty*7, x0 = tx*7;
    const int icg = blockIdx.y;
    const int n   = blockIdx.z;

    for (int it = 0; it < 16; ++it) {
        const int icA = icg*32 + it*2;
        const float* xA = x + ((size_t)n*ICn + icA) * (ISn*ISn*ISn);
        // ---- stage 2 ics of 11^3 x tile ----
        for (int u = tid; u < 2662; u += 256) {
            int t2 = (u >= 1331) ? 1 : 0; int rr = u - t2*1331;
            int z = rr/121; int r2 = rr - z*121; int yy = r2/11; int lx = r2 - yy*11;
            int gz = z0 - 3 + z, gy = y0 - 3 + yy, gx = x0 - 3 + lx;
            float v = 0.0f;
            if ((unsigned)gz < (unsigned)ISn && (unsigned)gy < (unsigned)ISn &&
                (unsigned)gx < (unsigned)ISn)
                v = xA[(size_t)t2*(ISn*ISn*ISn) + (gz*ISn + gy)*ISn + gx];
            xs[((t2*11 + z)*11 + yy)*12 + lx] = v;
        }
        __syncthreads();
        // ---- pass A along W: (11,11,11)->(11,11,8) ----
        if (tid < 242) {
            int t2 = (tid >= 121) ? 1 : 0; int rr = tid - t2*121;
            int z = rr/11, yy = rr - (rr/11)*11;
            const float* row = &xs[((t2*11 + z)*11 + yy)*12];
            float xr[12];
            #pragma unroll
            for (int j = 0; j < 12; ++j) xr[j] = row[j];
            float* orow = &as_[((t2*11 + z)*11 + yy)*8];
            #pragma unroll
            for (int u = 0; u < 8; ++u)
                orow[u] = K0f*(xr[u] + xr[u+4]) + K1f*(xr[u+1] + xr[u+2] + xr[u+3]);
        }
        __syncthreads();
        // ---- pass B along H: (11,11,7)->(11,7,7) ----
        if (tid < 154) {
            int t2 = (tid >= 77) ? 1 : 0; int rr = tid - t2*77;
            int z = rr/7, u = rr - (rr/7)*7;
            float ar[11];
            #pragma unroll
            for (int j = 0; j < 11; ++j) ar[j] = as_[((t2*11 + z)*11 + j)*8 + u];
            #pragma unroll
            for (int v = 0; v < 7; ++v)
                bs_[((t2*11 + z)*7 + v)*8 + u] =
                    K0f*(ar[v] + ar[v+4]) + K1f*(ar[v+1] + ar[v+2] + ar[v+3]);
        }
        __syncthreads();
        // ---- pass C along D: (11,7,7)->(7,7,7), write bf16 [ic][sp] ----
        if (tid < 98) {
            int t2 = (tid >= 49) ? 1 : 0; int rr = tid - t2*49;
            int v = rr/7, u = rr - (rr/7)*7;
            float br[11];
            #pragma unroll
            for (int j = 0; j < 11; ++j) br[j] = bs_[((t2*11 + j)*7 + v)*8 + u];
            const int icl = it*2 + t2;
            #pragma unroll
            for (int zo = 0; zo < 7; ++zo) {
                float f = K0f*(br[zo] + br[zo+4]) + K1f*(br[zo+1] + br[zo+2] + br[zo+3]);
                ysl[icl*343 + (zo*49 + v*7 + u)] = f2bf(f);
            }
        }
        __syncthreads();   // next stage overwrites xs only; A/B separated by later syncs
    }
    __syncthreads();
    // ---- flush: transpose LDS [ic][sp] -> global [sp][ic], 16B units ----
    for (int u2 = tid; u2 < 1372; u2 += 256) {
        int sp = u2 >> 2, icq = u2 & 3;
        int zo = sp/49; int r3 = sp - zo*49; int v = r3/7; int uu = r3 - v*7;
        unsigned pk[4];
        #pragma unroll
        for (int j = 0; j < 4; ++j) {
            unsigned lo = ysl[(icq*8 + 2*j    )*343 + sp];
            unsigned hi = ysl[(icq*8 + 2*j + 1)*343 + sp];
            pk[j] = lo | (hi << 16);
        }
        size_t g_sp = (size_t)(z0 + zo)*2401 + (size_t)(y0 + v)*49 + (x0 + uu);
        uint4 val = make_uint4(pk[0], pk[1], pk[2], pk[3]);
        *(uint4*)(yb + (((size_t)n*YV + g_sp)*ICn + icg*32 + icq*8)) = val;
    }
}

// ============================================================
// Kernel 2: conv via MFMA.  out(2,256,24^3) fp32
// block: 128 oc x 64 pts (4x4x4); 4 waves = 2(oc) x 2(pts)
// K-loop: 4 ic-chunks of 32; per chunk 27 taps, K=32 mfma
// A = w fragments direct from global wt (L2-resident)
// B = y tile staged in LDS [729 sp][36 shorts] (72B rows)
// ============================================================
#define PADW 36   // shorts per sp row (32 data + 4 pad = 72 B)
__global__ __launch_bounds__(256, 3) void conv_mfma(
    const unsigned short* __restrict__ wt,
    const unsigned short* __restrict__ yb,
    const float* __restrict__ bias,
    float* __restrict__ out)
{
    __shared__ unsigned short ys2[729 * PADW];   // 52488 B

    const int tid  = threadIdx.x;
    const int wav  = tid >> 6;
    const int lane = tid & 63;
    const int quad = lane >> 4;
    const int m    = lane & 15;
    const int wm   = wav & 1;       // oc half
    const int wn   = wav >> 1;      // pt half (od pairs)

    int bx = blockIdx.x;
    const int td = bx / 36; int r0 = bx - td*36;
    const int th = r0 / 6;  const int tw = r0 - th*6;
    const int g  = blockIdx.y;      // ocg
    const int n  = blockIdx.z;
    const int oc0 = g * 128;

    const int oh2 = (m >> 2) * 2;   // 2*oh
    const int ow2 = (m & 3) * 2;    // 2*ow

    // acc init from bias: oc = oc0 + wm*64 + mi*16 + quad*4 + r
    floatx4 acc[4][2];
    #pragma unroll
    for (int mi = 0; mi < 4; ++mi) {
        floatx4 bv = *(const floatx4*)(bias + oc0 + wm*64 + mi*16 + quad*4);
        acc[mi][0] = bv; acc[mi][1] = bv;
    }

    const short8* wt8 = (const short8*)wt;
    const size_t ybase = ((size_t)n * YV) * ICn;   // ushort index
    // y tile origin (8td, 8th, 8tw), extent 9 per axis (max 48 < 49, no bounds)
    const int gz0 = 8*td, gy0 = 8*th, gx0 = 8*tw;

    for (int ch = 0; ch < 4; ++ch) {
        if (ch) __syncthreads();
        // ---- stage y chunk: 729 sp x 32 ic -> LDS [sp][36] ----
        for (int idx = tid; idx < 2916; idx += 256) {
            int sp = idx >> 2, icq = idx & 3;
            int zs = sp / 81; int r = sp - zs*81; int ysv = r / 9; int xsv = r - ysv*9;
            size_t g_sp = (size_t)(gz0 + zs)*2401 + (size_t)(gy0 + ysv)*49 + (gx0 + xsv);
            uint4 val = *(const uint4*)(yb + (ybase + g_sp*ICn + ch*32 + icq*8));
            unsigned short* dst = &ys2[sp*PADW + icq*8];
            *(uint2*)(dst)     = make_uint2(val.x, val.y);
            *(uint2*)(dst + 4) = make_uint2(val.z, val.w);
        }
        __syncthreads();

        // ---- compute: 27 taps, K=32 over this ic chunk ----
        const int A0 = (g*108 + ch)*512 + (wm*64 + m)*4 + quad;  // short8 units
        #pragma unroll
        for (int a = 0; a < 3; ++a) {
            #pragma unroll
            for (int b = 0; b < 3; ++b) {
                #pragma unroll
                for (int c = 0; c < 3; ++c) {
                    const int t = a*9 + b*3 + c;
                    short8 A[4];
                    #pragma unroll
                    for (int mi = 0; mi < 4; ++mi)
                        A[mi] = wt8[A0 + t*2048 + mi*64];
                    short8 B[2];
                    #pragma unroll
                    for (int ni = 0; ni < 2; ++ni) {
                        const int zs = 2*(wn*2 + ni) + a;
                        const int sp = (zs*9 + oh2 + b)*9 + ow2 + c;
                        const unsigned short* p = &ys2[sp*PADW + quad*8];
                        short4v lo = *(const short4v*)(p);
                        short4v hi = *(const short4v*)(p + 4);
                        B[ni] = __builtin_shufflevector(lo, hi, 0,1,2,3,4,5,6,7);
                    }
                    #pragma unroll
                    for (int mi = 0; mi < 4; ++mi)
                        #pragma unroll
                        for (int ni = 0; ni < 2; ++ni)
                            acc[mi][ni] = __builtin_amdgcn_mfma_f32_16x16x32_bf16(
                                A[mi], B[ni], acc[mi][ni], 0, 0, 0);
                }
            }
        }
    }

    // ---- epilogue: D row = oc (quad*4+r), col = pt (lane&15) ----
    const int ohl = m >> 2, owl = m & 3;
    #pragma unroll
    for (int mi = 0; mi < 4; ++mi) {
        #pragma unroll
        for (int ni = 0; ni < 2; ++ni) {
            const int odl = wn*2 + ni;
            #pragma unroll
            for (int r = 0; r < 4; ++r) {
                const int oc = oc0 + wm*64 + mi*16 + quad*4 + r;
                size_t addr = ((((size_t)n*OCn + oc)*OSn + td*4 + odl)*OSn + th*4 + ohl)*OSn
                              + tw*4 + owl;
                out[addr] = acc[mi][ni][r];
            }
        }
    }
}

// ============================================================
// Fallback (round-1 fused fp32 kernel) if ws too small
// ============================================================
#define TD 4
#define TH 4
#define TW 8
#define XD 13
#define XH 13
#define XW 21
#define YW 17
#define YD 9
#define YH 9
#define XS_LEN (XD*XH*XW)
#define AS_OFF XS_LEN
#define AS_LEN (XD*XH*YW)
#define BS_OFF (AS_OFF + AS_LEN)
#define BS_LEN (XD*YH*YW)
#define WS_OFF 8412
#define WROW 136
#define LDS_TOT (WS_OFF + 27*WROW)

__global__ __launch_bounds__(256) void conv_down3d_fused(
    const float* __restrict__ x, const float* __restrict__ w,
    const float* __restrict__ bias, float* __restrict__ out)
{
    __shared__ float lds[LDS_TOT];
    float* xs = lds;
    float* as = lds + AS_OFF;
    float* bs = lds + BS_OFF;
    float* ws = lds + WS_OFF;
    float* ys = lds;

    const int tid = threadIdx.x;
    int s = blockIdx.x;
    const int tw = s % 3; s /= 3;
    const int th = s % 6; const int td = s / 6;
    const int od0 = td*TD, oh0 = th*TH, ow0 = tw*TW;
    const int oc0 = blockIdx.y * 128;
    const int n   = blockIdx.z;
    const int og = tid >> 4;
    const int pg = tid & 15;
    const int od = pg >> 2;
    const int oh = pg & 3;

    float acc[8][8];
    #pragma unroll
    for (int o = 0; o < 8; ++o) {
        const float bv = bias[oc0 + og*8 + o];
        #pragma unroll
        for (int p = 0; p < 8; ++p) acc[o][p] = bv;
    }

    const int x0d = 2*od0 - 3, x0h = 2*oh0 - 3, x0w = 2*ow0 - 3;
    const float* xn = x + (size_t)n * ICn * (ISn*ISn*ISn);
    const float* wg = w + (size_t)oc0 * (ICn*27);

    for (int ic = 0; ic < ICn; ++ic) {
        const float* xin = xn + (size_t)ic * (ISn*ISn*ISn);
        for (int idx = tid; idx < XS_LEN; idx += 256) {
            int lz = idx / (XH*XW);
            int r  = idx - lz*(XH*XW);
            int ly = r / XW;
            int lx = r - ly*XW;
            int gz = x0d + lz, gy = x0h + ly, gx = x0w + lx;
            float v = 0.0f;
            if ((unsigned)gz < (unsigned)ISn && (unsigned)gy < (unsigned)ISn &&
                (unsigned)gx < (unsigned)ISn)
                v = xin[((size_t)gz*ISn + gy)*ISn + gx];
            xs[idx] = v;
        }
        for (int idx = tid; idx < 27*128; idx += 256) {
            int oc  = idx / 27;
            int tap = idx - oc*27;
            ws[tap*WROW + oc] = wg[(size_t)oc*(ICn*27) + ic*27 + tap];
        }
        __syncthreads();
        for (int idx = tid; idx < AS_LEN; idx += 256) {
            int z = idx / (XH*YW);
            int r = idx - z*(XH*YW);
            int yy = r / YW;
            int u  = r - yy*YW;
            const float* p0 = &xs[(z*XH + yy)*XW + u];
            as[idx] = K0f*(p0[0] + p0[4]) + K1f*(p0[1] + p0[2] + p0[3]);
        }
        __syncthreads();
        for (int idx = tid; idx < BS_LEN; idx += 256) {
            int z = idx / (YH*YW);
            int r = idx - z*(YH*YW);
            int v = r / YW;
            int u = r - v*YW;
            const float* p0 = &as[(z*XH + v)*YW + u];
            bs[idx] = K0f*(p0[0] + p0[4*YW]) + K1f*(p0[YW] + p0[2*YW] + p0[3*YW]);
        }
        __syncthreads();
        for (int idx = tid; idx < YD*YH*YW; idx += 256) {
            int t = idx / (YH*YW);
            int r = idx - t*(YH*YW);
            int v = r / YW;
            int u = r - v*YW;
            const float* p0 = &bs[(t*YH + v)*YW + u];
            ys[idx] = K0f*(p0[0] + p0[4*(YH*YW)]) +
                      K1f*(p0[YH*YW] + p0[2*(YH*YW)] + p0[3*(YH*YW)]);
        }
        __syncthreads();
        #pragma unroll
        for (int a = 0; a < 3; ++a) {
            #pragma unroll
            for (int b = 0; b < 3; ++b) {
                const float* yrow = &ys[((2*od + a)*YH + (2*oh + b))*YW];
                #pragma unroll
                for (int c = 0; c < 3; ++c) {
                    float yv[8];
                    #pragma unroll
                    for (int p = 0; p < 8; ++p) yv[p] = yrow[2*p + c];
                    const float* wrow = &ws[(a*9 + b*3 + c)*WROW + og*8];
                    float wv[8];
                    #pragma unroll
                    for (int o = 0; o < 8; ++o) wv[o] = wrow[o];
                    #pragma unroll
                    for (int o = 0; o < 8; ++o)
                        #pragma unroll
                        for (int p = 0; p < 8; ++p)
                            acc[o][p] += wv[o] * yv[p];
                }
            }
        }
        __syncthreads();
    }
    #pragma unroll
    for (int o = 0; o < 8; ++o) {
        size_t base = ((((size_t)n*OCn + oc0 + og*8 + o)*OSn + (od0+od))*OSn + (oh0+oh))*OSn + ow0;
        float4 v0 = make_float4(acc[o][0], acc[o][1], acc[o][2], acc[o][3]);
        float4 v1 = make_float4(acc[o][4], acc[o][5], acc[o][6], acc[o][7]);
        *(float4*)(out + base)     = v0;
        *(float4*)(out + base + 4) = v1;
    }
}

// ============================================================
extern "C" void kernel_launch(void* const* d_in, const int* in_sizes, int n_in,
                              void* d_out, int out_size, void* d_ws, size_t ws_size,
                              hipStream_t stream) {
    const float* x    = (const float*)d_in[0];
    const float* w    = (const float*)d_in[1];
    const float* bias = (const float*)d_in[2];
    float* out        = (float*)d_out;

    const size_t WT_BYTES = (size_t)WT_ELEMS * 2;        // 1.77 MB
    const size_t Y_OFF    = 2097152;                     // 2 MB aligned
    const size_t Y_BYTES  = (size_t)2 * YV * ICn * 2;    // 60.2 MB
    const size_t WS_NEED  = Y_OFF + Y_BYTES;

    if (ws_size < WS_NEED) {
        // fallback: fused fp32 path (correct, slower)
        dim3 grid(6*6*3, OCn/128, 2);
        hipLaunchKernelGGL(conv_down3d_fused, grid, dim3(256), 0, stream, x, w, bias, out);
        return;
    }

    unsigned short* wt = (unsigned short*)d_ws;
    unsigned short* yb = (unsigned short*)((char*)d_ws + Y_OFF);

    hipLaunchKernelGGL(w_pack,     dim3(864),        dim3(256), 0, stream, w, wt);
    hipLaunchKernelGGL(fir_y_bf16, dim3(343, 4, 2),  dim3(256), 0, stream, x, yb);
    hipLaunchKernelGGL(conv_mfma,  dim3(216, 2, 2),  dim3(256), 0, stream, wt, yb, bias, out);
}

// Round 3
// 594.250 us; speedup vs baseline: 3.6643x; 1.1932x over previous
//
#include <hip/hip_runtime.h>

// ---------------- problem constants ----------------
#define ICn 128
#define OCn 256
#define ISn 48      // x spatial
#define YSn 49      // y (FIR out) spatial
#define OSn 24      // out spatial
#define YV  117649  // 49^3
#define K0f (1.0f/11.0f)
#define K1f (3.0f/11.0f)

typedef short  short8  __attribute__((ext_vector_type(8)));
typedef float  floatx4 __attribute__((ext_vector_type(4)));

static __device__ __forceinline__ unsigned short f2bf(float f) {
    union { float f; unsigned u; } v; v.f = f;
    unsigned r = (v.u + 0x7FFF + ((v.u >> 16) & 1)) >> 16;   // RNE
    return (unsigned short)r;
}

// ============================================================
// Kernel 0: repack w (fp32, [256][128][3][3][3]) -> bf16 wt in d_ws
// layout: wt[g=2][tap=27][chunk=4][oc=128][ic=32]
// ============================================================
#define WT_ELEMS (2*27*4*128*32)   // 884736
__global__ void w_pack(const float* __restrict__ w, unsigned short* __restrict__ wt) {
    int idx = blockIdx.x * 256 + threadIdx.x;
    const int stride = 864 * 256;
    for (; idx < WT_ELEMS; idx += stride) {
        int i  = idx & 31;
        int o  = (idx >> 5) & 127;
        int ch = (idx >> 12) & 3;
        int rest = idx >> 14;          // g*27 + t
        int t  = rest % 27;
        int g  = rest / 27;
        float v = w[(((size_t)(g*128 + o) * 128) + (ch*32 + i)) * 27 + t];
        wt[idx] = f2bf(v);
    }
}

// ============================================================
// Kernel 1: separable FIR  x(2,128,48^3) fp32 -> y bf16
// y layout (ch-blocked): yb[n][ch=4][sp=49^3][32 ic]  (64-B dense rows)
// tile: (7 z, 7 y, full 49 x); 8 ics per block; grid (49, 16, 2)
// LDS: xs (11,11,48) fp32 | ds (7,11,48) | hs (7,7,56) aliases xs
//      ysl: 2 ic-slices of 2401 bf16 (flush as packed uint every 2 ics)
// ============================================================
#define XS_F   (11*11*48)          // 5808 floats
#define DS_OFF XS_F                // ds at float offset 5808 (3696 floats)
#define YSL_F  (XS_F + 7*11*48)    // 9504 floats -> ysl (shorts) after
#define YSL_STRIDE 2404
#define FIR_LDS_F (YSL_F + (2*YSL_STRIDE + 1)/2)   // floats total

__global__ __launch_bounds__(256, 3) void fir_y_bf16(
    const float* __restrict__ x, unsigned short* __restrict__ yb)
{
    __shared__ float lds[FIR_LDS_F];   // 47632 B
    float* xs = lds;                         // (11,11,48)
    float* ds = lds + DS_OFF;                // (7,11,48)
    float* hs = lds;                         // (7,7,56)  aliases xs
    unsigned short* ysl = (unsigned short*)(lds + YSL_F);

    const int tid = threadIdx.x;
    const int tz = blockIdx.x / 7, ty = blockIdx.x % 7;
    const int z0 = tz*7, y0 = ty*7;
    const int icg = blockIdx.y;      // 16 groups of 8 ics
    const int n   = blockIdx.z;
    const int ch  = icg >> 2;
    const int slot0 = (icg & 3) * 8;

    const size_t xbase = ((size_t)n*ICn + icg*8) * (ISn*ISn*ISn);
    const size_t ybase = (((size_t)n*4 + ch) * YV) * 32;

    for (int ic = 0; ic < 8; ++ic) {
        // ---- stage x tile: 121 rows x 12 float4 (fully coalesced) ----
        const float* xin = x + xbase + (size_t)ic * (ISn*ISn*ISn);
        for (int idx = tid; idx < 1452; idx += 256) {
            int r = idx / 12, c = idx - r*12;
            int d = r / 11, yy = r - d*11;
            int gz = z0 - 3 + d, gy = y0 - 3 + yy;
            floatx4 v = {0.f, 0.f, 0.f, 0.f};
            if ((unsigned)gz < (unsigned)ISn && (unsigned)gy < (unsigned)ISn)
                v = *(const floatx4*)(xin + ((size_t)gz*ISn + gy)*ISn + 4*c);
            *(floatx4*)(xs + (size_t)r*48 + 4*c) = v;
        }
        __syncthreads();
        // ---- pass D (z): (11,11,48) -> (7,11,48), float4 ----
        for (int idx = tid; idx < 924; idx += 256) {
            int z = idx / 132; int rem = idx - z*132;
            int yy = rem / 12, c = rem - (rem/12)*12;
            const float* p = xs + ((size_t)z*11 + yy)*48 + 4*c;
            floatx4 a0 = *(const floatx4*)(p);
            floatx4 a1 = *(const floatx4*)(p + 528);
            floatx4 a2 = *(const floatx4*)(p + 1056);
            floatx4 a3 = *(const floatx4*)(p + 1584);
            floatx4 a4 = *(const floatx4*)(p + 2112);
            *(floatx4*)(ds + ((size_t)z*11 + yy)*48 + 4*c) =
                K0f*(a0 + a4) + K1f*(a1 + a2 + a3);
        }
        __syncthreads();
        // ---- pass H (y): (7,11,48) -> hs (7,7,56) with zero x-pads ----
        for (int idx = tid; idx < 686; idx += 256) {
            int z = idx / 98; int rem = idx - z*98;
            int yy = rem / 14, c = rem - (rem/14)*14;
            float* dst = hs + ((size_t)z*7 + yy)*56 + 4*c;
            if (c == 0 || c == 13) {
                floatx4 zz = {0.f,0.f,0.f,0.f};
                *(floatx4*)dst = zz;
            } else {
                const float* p = ds + ((size_t)z*11 + yy)*48 + 4*(c-1);
                floatx4 a0 = *(const floatx4*)(p);
                floatx4 a1 = *(const floatx4*)(p + 48);
                floatx4 a2 = *(const floatx4*)(p + 96);
                floatx4 a3 = *(const floatx4*)(p + 144);
                floatx4 a4 = *(const floatx4*)(p + 192);
                *(floatx4*)dst = K0f*(a0 + a4) + K1f*(a1 + a2 + a3);
            }
        }
        __syncthreads();
        // ---- pass W (x): (7,7,[48]) -> 2401 bf16 into ysl slice ----
        unsigned short* ysw = ysl + (ic & 1) * YSL_STRIDE;
        for (int idx = tid; idx < 2401; idx += 256) {
            int zl = idx / 343; int rem = idx - zl*343;
            int yl = rem / 49, u = rem - (rem/49)*49;
            const float* p = hs + ((size_t)zl*7 + yl)*56 + u + 1;
            float v = K0f*(p[0] + p[4]) + K1f*(p[1] + p[2] + p[3]);
            ysw[idx] = f2bf(v);
        }
        __syncthreads();
        // ---- flush every 2 ics: pack pair -> uint store ----
        if (ic & 1) {
            const int slot = slot0 + (ic >> 1) * 2;
            for (int idx = tid; idx < 2401; idx += 256) {
                unsigned lo = ysl[idx];
                unsigned hi = ysl[YSL_STRIDE + idx];
                int zl = idx / 343; int rem = idx - zl*343;
                int yl = rem / 49, u = rem - (rem/49)*49;
                size_t g_sp = (size_t)(z0+zl)*2401 + (size_t)(y0+yl)*49 + u;
                *(unsigned*)(yb + ybase + g_sp*32 + slot) = lo | (hi << 16);
            }
            __syncthreads();
        }
    }
}

// ============================================================
// Kernel 2: conv via MFMA.  out(2,256,24^3) fp32
// block: 128 oc x 64 pts (4x4x4); 4 waves = 2(oc) x 2(pts)
// B tile LDS layout [icq=4][729 sp][8 shorts]: B-frag = ONE aligned
// ds_read_b128, uniform 8-lane/granule (conflict-free minimum).
// ============================================================
__global__ __launch_bounds__(256, 3) void conv_mfma(
    const unsigned short* __restrict__ wt,
    const unsigned short* __restrict__ yb,
    const float* __restrict__ bias,
    float* __restrict__ out)
{
    __shared__ unsigned short ys3[4*729*8];   // 46656 B

    const int tid  = threadIdx.x;
    const int wav  = tid >> 6;
    const int lane = tid & 63;
    const int quad = lane >> 4;
    const int m    = lane & 15;
    const int wm   = wav & 1;       // oc half
    const int wn   = wav >> 1;      // pt half (od pairs)

    int bx = blockIdx.x;
    const int td = bx / 36; int r0 = bx - td*36;
    const int th = r0 / 6;  const int tw = r0 - th*6;
    const int g  = blockIdx.y;      // ocg
    const int n  = blockIdx.z;
    const int oc0 = g * 128;

    const int oh2 = (m >> 2) * 2;
    const int ow2 = (m & 3) * 2;

    floatx4 acc[4][2];
    #pragma unroll
    for (int mi = 0; mi < 4; ++mi) {
        floatx4 bv = *(const floatx4*)(bias + oc0 + wm*64 + mi*16 + quad*4);
        acc[mi][0] = bv; acc[mi][1] = bv;
    }

    const short8* wt8 = (const short8*)wt;
    const int gz0 = 8*td, gy0 = 8*th, gx0 = 8*tw;

    for (int chk = 0; chk < 4; ++chk) {
        if (chk) __syncthreads();
        const size_t ybase = (((size_t)n*4 + chk) * YV) * 32;
        // ---- stage y chunk: 729 sp x 32 ic (dense 64-B lines) ----
        for (int idx = tid; idx < 2916; idx += 256) {
            int sp = idx >> 2, icq = idx & 3;
            int zs = sp / 81; int r = sp - zs*81; int ysv = r / 9; int xsv = r - ysv*9;
            size_t g_sp = (size_t)(gz0 + zs)*2401 + (size_t)(gy0 + ysv)*49 + (gx0 + xsv);
            uint4 val = *(const uint4*)(yb + ybase + g_sp*32 + icq*8);
            *(uint4*)(&ys3[((size_t)icq*729 + sp)*8]) = val;
        }
        __syncthreads();

        // ---- compute: 27 taps, K=32 mfma ----
        const int A0 = (g*108 + chk)*512 + (wm*64 + m)*4 + quad;  // short8 units
        #pragma unroll
        for (int a = 0; a < 3; ++a) {
            #pragma unroll
            for (int b = 0; b < 3; ++b) {
                #pragma unroll
                for (int c = 0; c < 3; ++c) {
                    const int t = a*9 + b*3 + c;
                    short8 A[4];
                    #pragma unroll
                    for (int mi = 0; mi < 4; ++mi)
                        A[mi] = wt8[A0 + t*2048 + mi*64];
                    short8 B[2];
                    #pragma unroll
                    for (int ni = 0; ni < 2; ++ni) {
                        const int zs = 2*(wn*2 + ni) + a;
                        const int sp = (zs*9 + oh2 + b)*9 + ow2 + c;
                        B[ni] = *(const short8*)(&ys3[((size_t)quad*729 + sp)*8]);
                    }
                    #pragma unroll
                    for (int mi = 0; mi < 4; ++mi)
                        #pragma unroll
                        for (int ni = 0; ni < 2; ++ni)
                            acc[mi][ni] = __builtin_amdgcn_mfma_f32_16x16x32_bf16(
                                A[mi], B[ni], acc[mi][ni], 0, 0, 0);
                }
            }
        }
    }

    // ---- epilogue: D row = oc (quad*4+r), col = pt (lane&15) ----
    const int ohl = m >> 2, owl = m & 3;
    #pragma unroll
    for (int mi = 0; mi < 4; ++mi) {
        #pragma unroll
        for (int ni = 0; ni < 2; ++ni) {
            const int odl = wn*2 + ni;
            #pragma unroll
            for (int r = 0; r < 4; ++r) {
                const int oc = oc0 + wm*64 + mi*16 + quad*4 + r;
                size_t addr = ((((size_t)n*OCn + oc)*OSn + td*4 + odl)*OSn + th*4 + ohl)*OSn
                              + tw*4 + owl;
                out[addr] = acc[mi][ni][r];
            }
        }
    }
}

// ============================================================
// Fallback (round-1 fused fp32 kernel) if ws too small
// ============================================================
#define TD 4
#define TH 4
#define TW 8
#define XD 13
#define XH 13
#define XW 21
#define YW 17
#define YD 9
#define YH 9
#define XS_LEN (XD*XH*XW)
#define AS_OFF XS_LEN
#define AS_LEN (XD*XH*YW)
#define BS_OFF (AS_OFF + AS_LEN)
#define BS_LEN (XD*YH*YW)
#define WS_OFF 8412
#define WROW 136
#define LDS_TOT (WS_OFF + 27*WROW)

__global__ __launch_bounds__(256) void conv_down3d_fused(
    const float* __restrict__ x, const float* __restrict__ w,
    const float* __restrict__ bias, float* __restrict__ out)
{
    __shared__ float lds[LDS_TOT];
    float* xs = lds;
    float* as = lds + AS_OFF;
    float* bs = lds + BS_OFF;
    float* ws = lds + WS_OFF;
    float* ys = lds;

    const int tid = threadIdx.x;
    int s = blockIdx.x;
    const int tw = s % 3; s /= 3;
    const int th = s % 6; const int td = s / 6;
    const int od0 = td*TD, oh0 = th*TH, ow0 = tw*TW;
    const int oc0 = blockIdx.y * 128;
    const int n   = blockIdx.z;
    const int og = tid >> 4;
    const int pg = tid & 15;
    const int od = pg >> 2;
    const int oh = pg & 3;

    float acc[8][8];
    #pragma unroll
    for (int o = 0; o < 8; ++o) {
        const float bv = bias[oc0 + og*8 + o];
        #pragma unroll
        for (int p = 0; p < 8; ++p) acc[o][p] = bv;
    }

    const int x0d = 2*od0 - 3, x0h = 2*oh0 - 3, x0w = 2*ow0 - 3;
    const float* xn = x + (size_t)n * ICn * (ISn*ISn*ISn);
    const float* wg = w + (size_t)oc0 * (ICn*27);

    for (int ic = 0; ic < ICn; ++ic) {
        const float* xin = xn + (size_t)ic * (ISn*ISn*ISn);
        for (int idx = tid; idx < XS_LEN; idx += 256) {
            int lz = idx / (XH*XW);
            int r  = idx - lz*(XH*XW);
            int ly = r / XW;
            int lx = r - ly*XW;
            int gz = x0d + lz, gy = x0h + ly, gx = x0w + lx;
            float v = 0.0f;
            if ((unsigned)gz < (unsigned)ISn && (unsigned)gy < (unsigned)ISn &&
                (unsigned)gx < (unsigned)ISn)
                v = xin[((size_t)gz*ISn + gy)*ISn + gx];
            xs[idx] = v;
        }
        for (int idx = tid; idx < 27*128; idx += 256) {
            int oc  = idx / 27;
            int tap = idx - oc*27;
            ws[tap*WROW + oc] = wg[(size_t)oc*(ICn*27) + ic*27 + tap];
        }
        __syncthreads();
        for (int idx = tid; idx < AS_LEN; idx += 256) {
            int z = idx / (XH*YW);
            int r = idx - z*(XH*YW);
            int yy = r / YW;
            int u  = r - yy*YW;
            const float* p0 = &xs[(z*XH + yy)*XW + u];
            as[idx] = K0f*(p0[0] + p0[4]) + K1f*(p0[1] + p0[2] + p0[3]);
        }
        __syncthreads();
        for (int idx = tid; idx < BS_LEN; idx += 256) {
            int z = idx / (YH*YW);
            int r = idx - z*(YH*YW);
            int v = r / YW;
            int u = r - v*YW;
            const float* p0 = &as[(z*XH + v)*YW + u];
            bs[idx] = K0f*(p0[0] + p0[4*YW]) + K1f*(p0[YW] + p0[2*YW] + p0[3*YW]);
        }
        __syncthreads();
        for (int idx = tid; idx < YD*YH*YW; idx += 256) {
            int t = idx / (YH*YW);
            int r = idx - t*(YH*YW);
            int v = r / YW;
            int u = r - v*YW;
            const float* p0 = &bs[(t*YH + v)*YW + u];
            ys[idx] = K0f*(p0[0] + p0[4*(YH*YW)]) +
                      K1f*(p0[YH*YW] + p0[2*(YH*YW)] + p0[3*(YH*YW)]);
        }
        __syncthreads();
        #pragma unroll
        for (int a = 0; a < 3; ++a) {
            #pragma unroll
            for (int b = 0; b < 3; ++b) {
                const float* yrow = &ys[((2*od + a)*YH + (2*oh + b))*YW];
                #pragma unroll
                for (int c = 0; c < 3; ++c) {
                    float yv[8];
                    #pragma unroll
                    for (int p = 0; p < 8; ++p) yv[p] = yrow[2*p + c];
                    const float* wrow = &ws[(a*9 + b*3 + c)*WROW + og*8];
                    float wv[8];
                    #pragma unroll
                    for (int o = 0; o < 8; ++o) wv[o] = wrow[o];
                    #pragma unroll
                    for (int o = 0; o < 8; ++o)
                        #pragma unroll
                        for (int p = 0; p < 8; ++p)
                            acc[o][p] += wv[o] * yv[p];
                }
            }
        }
        __syncthreads();
    }
    #pragma unroll
    for (int o = 0; o < 8; ++o) {
        size_t base = ((((size_t)n*OCn + oc0 + og*8 + o)*OSn + (od0+od))*OSn + (oh0+oh))*OSn + ow0;
        float4 v0 = make_float4(acc[o][0], acc[o][1], acc[o][2], acc[o][3]);
        float4 v1 = make_float4(acc[o][4], acc[o][5], acc[o][6], acc[o][7]);
        *(float4*)(out + base)     = v0;
        *(float4*)(out + base + 4) = v1;
    }
}

// ============================================================
extern "C" void kernel_launch(void* const* d_in, const int* in_sizes, int n_in,
                              void* d_out, int out_size, void* d_ws, size_t ws_size,
                              hipStream_t stream) {
    const float* x    = (const float*)d_in[0];
    const float* w    = (const float*)d_in[1];
    const float* bias = (const float*)d_in[2];
    float* out        = (float*)d_out;

    const size_t Y_OFF    = 2097152;                     // 2 MB aligned
    const size_t Y_BYTES  = (size_t)2 * 4 * YV * 32 * 2; // 60.2 MB
    const size_t WS_NEED  = Y_OFF + Y_BYTES;

    if (ws_size < WS_NEED) {
        dim3 grid(6*6*3, OCn/128, 2);
        hipLaunchKernelGGL(conv_down3d_fused, grid, dim3(256), 0, stream, x, w, bias, out);
        return;
    }

    unsigned short* wt = (unsigned short*)d_ws;
    unsigned short* yb = (unsigned short*)((char*)d_ws + Y_OFF);

    hipLaunchKernelGGL(w_pack,     dim3(864),        dim3(256), 0, stream, w, wt);
    hipLaunchKernelGGL(fir_y_bf16, dim3(49, 16, 2),  dim3(256), 0, stream, x, yb);
    hipLaunchKernelGGL(conv_mfma,  dim3(216, 2, 2),  dim3(256), 0, stream, wt, yb, bias, out);
}

// Round 4
// 501.484 us; speedup vs baseline: 4.3421x; 1.1850x over previous
//
#include <hip/hip_runtime.h>

// ---------------- problem constants ----------------
#define ICn 128
#define OCn 256
#define ISn 48      // x spatial
#define YSn 49      // y (FIR out) spatial
#define OSn 24      // out spatial
#define YV  117649  // 49^3
#define K0f (1.0f/11.0f)
#define K1f (3.0f/11.0f)

typedef short  short8  __attribute__((ext_vector_type(8)));
typedef float  floatx4 __attribute__((ext_vector_type(4)));

static __device__ __forceinline__ unsigned short f2bf(float f) {
    union { float f; unsigned u; } v; v.f = f;
    unsigned r = (v.u + 0x7FFF + ((v.u >> 16) & 1)) >> 16;   // RNE
    return (unsigned short)r;
}

// ============================================================
// Kernel 0: repack w (fp32, [256][128][3][3][3]) -> bf16 wt in d_ws
// layout: wt[g=2][tap=27][chunk=4][oc=128][ic=32]
// ============================================================
#define WT_ELEMS (2*27*4*128*32)   // 884736
__global__ void w_pack(const float* __restrict__ w, unsigned short* __restrict__ wt) {
    int idx = blockIdx.x * 256 + threadIdx.x;
    const int stride = 864 * 256;
    for (; idx < WT_ELEMS; idx += stride) {
        int i  = idx & 31;
        int o  = (idx >> 5) & 127;
        int ch = (idx >> 12) & 3;
        int rest = idx >> 14;          // g*27 + t
        int t  = rest % 27;
        int g  = rest / 27;
        float v = w[(((size_t)(g*128 + o) * 128) + (ch*32 + i)) * 27 + t];
        wt[idx] = f2bf(v);
    }
}

// ============================================================
// Kernel 1: separable FIR  x(2,128,48^3) fp32 -> y bf16
// y layout: yb[n][icg=16][sp=49^3][8 ic]  (16-B dense rows)
// tile: (7 z, 7 y, full 49 x); 8 ics per block; grid (49, 16, 2)
// All 8 ic-slices accumulate in LDS; ONE flush of dense 16-B stores
// (full-line coverage -> no partial-line write RMW).
// ============================================================
#define XS_F   (11*11*48)          // 5808 floats
#define DS_OFF XS_F                // ds at float offset 5808 (3696 floats)
#define YSL_F  (XS_F + 7*11*48)    // 9504 floats -> ysl (shorts) after
#define YSL_STR 2404               // shorts per ic slice (pad from 2401)
#define FIR_LDS_F (YSL_F + (8*YSL_STR)/2)   // 19120 floats = 76480 B

__global__ __launch_bounds__(256, 2) void fir_y_bf16(
    const float* __restrict__ x, unsigned short* __restrict__ yb)
{
    __shared__ float lds[FIR_LDS_F];
    float* xs = lds;                         // (11,11,48)
    float* ds = lds + DS_OFF;                // (7,11,48)
    float* hs = lds;                         // (7,7,56)  aliases xs
    unsigned short* ysl = (unsigned short*)(lds + YSL_F);   // 8 x 2404

    const int tid = threadIdx.x;
    const int tz = blockIdx.x / 7, ty = blockIdx.x % 7;
    const int z0 = tz*7, y0 = ty*7;
    const int icg = blockIdx.y;      // 16 groups of 8 ics
    const int n   = blockIdx.z;

    const size_t xbase = ((size_t)n*ICn + icg*8) * (ISn*ISn*ISn);
    const size_t ybase = ((size_t)(n*16 + icg)) * YV * 8;   // ushort index

    for (int ic = 0; ic < 8; ++ic) {
        // ---- stage x tile: 121 rows x 12 float4 (fully coalesced) ----
        const float* xin = x + xbase + (size_t)ic * (ISn*ISn*ISn);
        for (int idx = tid; idx < 1452; idx += 256) {
            int r = idx / 12, c = idx - r*12;
            int d = r / 11, yy = r - d*11;
            int gz = z0 - 3 + d, gy = y0 - 3 + yy;
            floatx4 v = {0.f, 0.f, 0.f, 0.f};
            if ((unsigned)gz < (unsigned)ISn && (unsigned)gy < (unsigned)ISn)
                v = *(const floatx4*)(xin + ((size_t)gz*ISn + gy)*ISn + 4*c);
            *(floatx4*)(xs + (size_t)r*48 + 4*c) = v;
        }
        __syncthreads();
        // ---- pass D (z): (11,11,48) -> (7,11,48), float4 ----
        for (int idx = tid; idx < 924; idx += 256) {
            int z = idx / 132; int rem = idx - z*132;
            int yy = rem / 12, c = rem - (rem/12)*12;
            const float* p = xs + ((size_t)z*11 + yy)*48 + 4*c;
            floatx4 a0 = *(const floatx4*)(p);
            floatx4 a1 = *(const floatx4*)(p + 528);
            floatx4 a2 = *(const floatx4*)(p + 1056);
            floatx4 a3 = *(const floatx4*)(p + 1584);
            floatx4 a4 = *(const floatx4*)(p + 2112);
            *(floatx4*)(ds + ((size_t)z*11 + yy)*48 + 4*c) =
                K0f*(a0 + a4) + K1f*(a1 + a2 + a3);
        }
        __syncthreads();
        // ---- pass H (y): (7,11,48) -> hs (7,7,56) with zero x-pads ----
        for (int idx = tid; idx < 686; idx += 256) {
            int z = idx / 98; int rem = idx - z*98;
            int yy = rem / 14, c = rem - (rem/14)*14;
            float* dst = hs + ((size_t)z*7 + yy)*56 + 4*c;
            if (c == 0 || c == 13) {
                floatx4 zz = {0.f,0.f,0.f,0.f};
                *(floatx4*)dst = zz;
            } else {
                const float* p = ds + ((size_t)z*11 + yy)*48 + 4*(c-1);
                floatx4 a0 = *(const floatx4*)(p);
                floatx4 a1 = *(const floatx4*)(p + 48);
                floatx4 a2 = *(const floatx4*)(p + 96);
                floatx4 a3 = *(const floatx4*)(p + 144);
                floatx4 a4 = *(const floatx4*)(p + 192);
                *(floatx4*)dst = K0f*(a0 + a4) + K1f*(a1 + a2 + a3);
            }
        }
        __syncthreads();
        // ---- pass W (x): (7,7,[48]) -> 2401 bf16 into ysl slice ic ----
        unsigned short* ysw = ysl + ic * YSL_STR;
        for (int idx = tid; idx < 2401; idx += 256) {
            int zl = idx / 343; int rem = idx - zl*343;
            int yl = rem / 49, u = rem - (rem/49)*49;
            const float* p = hs + ((size_t)zl*7 + yl)*56 + u + 1;
            float v = K0f*(p[0] + p[4]) + K1f*(p[1] + p[2] + p[3]);
            ysw[idx] = f2bf(v);
        }
        __syncthreads();   // protects hs(=xs) before next stage / before flush
    }

    // ---- single flush: pack 8 ics -> uint4, dense contiguous stores ----
    for (int idx = tid; idx < 2401; idx += 256) {
        unsigned u0 = (unsigned)ysl[0*YSL_STR + idx] | ((unsigned)ysl[1*YSL_STR + idx] << 16);
        unsigned u1 = (unsigned)ysl[2*YSL_STR + idx] | ((unsigned)ysl[3*YSL_STR + idx] << 16);
        unsigned u2 = (unsigned)ysl[4*YSL_STR + idx] | ((unsigned)ysl[5*YSL_STR + idx] << 16);
        unsigned u3 = (unsigned)ysl[6*YSL_STR + idx] | ((unsigned)ysl[7*YSL_STR + idx] << 16);
        int zl = idx / 343; int rem = idx - zl*343;
        int yl = rem / 49, u = rem - (rem/49)*49;
        size_t g_sp = (size_t)(z0+zl)*2401 + (size_t)(y0+yl)*49 + u;
        *(uint4*)(yb + ybase + g_sp*8) = make_uint4(u0, u1, u2, u3);
    }
}

// ============================================================
// Kernel 2: conv via MFMA.  out(2,256,24^3) fp32
// block: 128 oc x 64 pts (4x4x4); 4 waves = 2(oc) x 2(pts)
// B tile LDS layout [icq=4][729 sp][8 shorts]: B-frag = ONE aligned
// ds_read_b128, uniform 8-lane/granule.
// ============================================================
__global__ __launch_bounds__(256, 3) void conv_mfma(
    const unsigned short* __restrict__ wt,
    const unsigned short* __restrict__ yb,
    const float* __restrict__ bias,
    float* __restrict__ out)
{
    __shared__ unsigned short ys3[4*729*8];   // 46656 B

    const int tid  = threadIdx.x;
    const int wav  = tid >> 6;
    const int lane = tid & 63;
    const int quad = lane >> 4;
    const int m    = lane & 15;
    const int wm   = wav & 1;       // oc half
    const int wn   = wav >> 1;      // pt half (od pairs)

    int bx = blockIdx.x;
    const int td = bx / 36; int r0 = bx - td*36;
    const int th = r0 / 6;  const int tw = r0 - th*6;
    const int g  = blockIdx.y;      // ocg
    const int n  = blockIdx.z;
    const int oc0 = g * 128;

    const int oh2 = (m >> 2) * 2;
    const int ow2 = (m & 3) * 2;

    floatx4 acc[4][2];
    #pragma unroll
    for (int mi = 0; mi < 4; ++mi) {
        floatx4 bv = *(const floatx4*)(bias + oc0 + wm*64 + mi*16 + quad*4);
        acc[mi][0] = bv; acc[mi][1] = bv;
    }

    const short8* wt8 = (const short8*)wt;
    const int gz0 = 8*td, gy0 = 8*th, gx0 = 8*tw;

    for (int chk = 0; chk < 4; ++chk) {
        if (chk) __syncthreads();
        // ---- stage y chunk: 4 icg regions x 729 sp (lane-contiguous sp) ----
        for (int idx = tid; idx < 2916; idx += 256) {
            int icq = idx / 729, sp = idx - icq*729;
            int zs = sp / 81; int r = sp - zs*81; int ysv = r / 9; int xsv = r - ysv*9;
            size_t g_sp = (size_t)(gz0 + zs)*2401 + (size_t)(gy0 + ysv)*49 + (gx0 + xsv);
            const unsigned short* src =
                yb + ((size_t)(n*16 + chk*4 + icq)) * YV * 8 + g_sp*8;
            uint4 val = *(const uint4*)src;
            *(uint4*)(&ys3[((size_t)icq*729 + sp)*8]) = val;
        }
        __syncthreads();

        // ---- compute: 27 taps, K=32 mfma ----
        const int A0 = (g*108 + chk)*512 + (wm*64 + m)*4 + quad;  // short8 units
        #pragma unroll
        for (int a = 0; a < 3; ++a) {
            #pragma unroll
            for (int b = 0; b < 3; ++b) {
                #pragma unroll
                for (int c = 0; c < 3; ++c) {
                    const int t = a*9 + b*3 + c;
                    short8 A[4];
                    #pragma unroll
                    for (int mi = 0; mi < 4; ++mi)
                        A[mi] = wt8[A0 + t*2048 + mi*64];
                    short8 B[2];
                    #pragma unroll
                    for (int ni = 0; ni < 2; ++ni) {
                        const int zs = 2*(wn*2 + ni) + a;
                        const int sp = (zs*9 + oh2 + b)*9 + ow2 + c;
                        B[ni] = *(const short8*)(&ys3[((size_t)quad*729 + sp)*8]);
                    }
                    #pragma unroll
                    for (int mi = 0; mi < 4; ++mi)
                        #pragma unroll
                        for (int ni = 0; ni < 2; ++ni)
                            acc[mi][ni] = __builtin_amdgcn_mfma_f32_16x16x32_bf16(
                                A[mi], B[ni], acc[mi][ni], 0, 0, 0);
                }
            }
        }
    }

    // ---- epilogue: D row = oc (quad*4+r), col = pt (lane&15) ----
    const int ohl = m >> 2, owl = m & 3;
    #pragma unroll
    for (int mi = 0; mi < 4; ++mi) {
        #pragma unroll
        for (int ni = 0; ni < 2; ++ni) {
            const int odl = wn*2 + ni;
            #pragma unroll
            for (int r = 0; r < 4; ++r) {
                const int oc = oc0 + wm*64 + mi*16 + quad*4 + r;
                size_t addr = ((((size_t)n*OCn + oc)*OSn + td*4 + odl)*OSn + th*4 + ohl)*OSn
                              + tw*4 + owl;
                out[addr] = acc[mi][ni][r];
            }
        }
    }
}

// ============================================================
// Fallback (round-1 fused fp32 kernel) if ws too small
// ============================================================
#define TD 4
#define TH 4
#define TW 8
#define XD 13
#define XH 13
#define XW 21
#define YW 17
#define YD 9
#define YH 9
#define XS_LEN (XD*XH*XW)
#define AS_OFF XS_LEN
#define AS_LEN (XD*XH*YW)
#define BS_OFF (AS_OFF + AS_LEN)
#define BS_LEN (XD*YH*YW)
#define WS_OFF 8412
#define WROW 136
#define LDS_TOT (WS_OFF + 27*WROW)

__global__ __launch_bounds__(256) void conv_down3d_fused(
    const float* __restrict__ x, const float* __restrict__ w,
    const float* __restrict__ bias, float* __restrict__ out)
{
    __shared__ float lds[LDS_TOT];
    float* xs = lds;
    float* as = lds + AS_OFF;
    float* bs = lds + BS_OFF;
    float* ws = lds + WS_OFF;
    float* ys = lds;

    const int tid = threadIdx.x;
    int s = blockIdx.x;
    const int tw = s % 3; s /= 3;
    const int th = s % 6; const int td = s / 6;
    const int od0 = td*TD, oh0 = th*TH, ow0 = tw*TW;
    const int oc0 = blockIdx.y * 128;
    const int n   = blockIdx.z;
    const int og = tid >> 4;
    const int pg = tid & 15;
    const int od = pg >> 2;
    const int oh = pg & 3;

    float acc[8][8];
    #pragma unroll
    for (int o = 0; o < 8; ++o) {
        const float bv = bias[oc0 + og*8 + o];
        #pragma unroll
        for (int p = 0; p < 8; ++p) acc[o][p] = bv;
    }

    const int x0d = 2*od0 - 3, x0h = 2*oh0 - 3, x0w = 2*ow0 - 3;
    const float* xn = x + (size_t)n * ICn * (ISn*ISn*ISn);
    const float* wg = w + (size_t)oc0 * (ICn*27);

    for (int ic = 0; ic < ICn; ++ic) {
        const float* xin = xn + (size_t)ic * (ISn*ISn*ISn);
        for (int idx = tid; idx < XS_LEN; idx += 256) {
            int lz = idx / (XH*XW);
            int r  = idx - lz*(XH*XW);
            int ly = r / XW;
            int lx = r - ly*XW;
            int gz = x0d + lz, gy = x0h + ly, gx = x0w + lx;
            float v = 0.0f;
            if ((unsigned)gz < (unsigned)ISn && (unsigned)gy < (unsigned)ISn &&
                (unsigned)gx < (unsigned)ISn)
                v = xin[((size_t)gz*ISn + gy)*ISn + gx];
            xs[idx] = v;
        }
        for (int idx = tid; idx < 27*128; idx += 256) {
            int oc  = idx / 27;
            int tap = idx - oc*27;
            ws[tap*WROW + oc] = wg[(size_t)oc*(ICn*27) + ic*27 + tap];
        }
        __syncthreads();
        for (int idx = tid; idx < AS_LEN; idx += 256) {
            int z = idx / (XH*YW);
            int r = idx - z*(XH*YW);
            int yy = r / YW;
            int u  = r - yy*YW;
            const float* p0 = &xs[(z*XH + yy)*XW + u];
            as[idx] = K0f*(p0[0] + p0[4]) + K1f*(p0[1] + p0[2] + p0[3]);
        }
        __syncthreads();
        for (int idx = tid; idx < BS_LEN; idx += 256) {
            int z = idx / (YH*YW);
            int r = idx - z*(YH*YW);
            int v = r / YW;
            int u = r - v*YW;
            const float* p0 = &as[(z*XH + v)*YW + u];
            bs[idx] = K0f*(p0[0] + p0[4*YW]) + K1f*(p0[YW] + p0[2*YW] + p0[3*YW]);
        }
        __syncthreads();
        for (int idx = tid; idx < YD*YH*YW; idx += 256) {
            int t = idx / (YH*YW);
            int r = idx - t*(YH*YW);
            int v = r / YW;
            int u = r - v*YW;
            const float* p0 = &bs[(t*YH + v)*YW + u];
            ys[idx] = K0f*(p0[0] + p0[4*(YH*YW)]) +
                      K1f*(p0[YH*YW] + p0[2*(YH*YW)] + p0[3*(YH*YW)]);
        }
        __syncthreads();
        #pragma unroll
        for (int a = 0; a < 3; ++a) {
            #pragma unroll
            for (int b = 0; b < 3; ++b) {
                const float* yrow = &ys[((2*od + a)*YH + (2*oh + b))*YW];
                #pragma unroll
                for (int c = 0; c < 3; ++c) {
                    float yv[8];
                    #pragma unroll
                    for (int p = 0; p < 8; ++p) yv[p] = yrow[2*p + c];
                    const float* wrow = &ws[(a*9 + b*3 + c)*WROW + og*8];
                    float wv[8];
                    #pragma unroll
                    for (int o = 0; o < 8; ++o) wv[o] = wrow[o];
                    #pragma unroll
                    for (int o = 0; o < 8; ++o)
                        #pragma unroll
                        for (int p = 0; p < 8; ++p)
                            acc[o][p] += wv[o] * yv[p];
                }
            }
        }
        __syncthreads();
    }
    #pragma unroll
    for (int o = 0; o < 8; ++o) {
        size_t base = ((((size_t)n*OCn + oc0 + og*8 + o)*OSn + (od0+od))*OSn + (oh0+oh))*OSn + ow0;
        float4 v0 = make_float4(acc[o][0], acc[o][1], acc[o][2], acc[o][3]);
        float4 v1 = make_float4(acc[o][4], acc[o][5], acc[o][6], acc[o][7]);
        *(float4*)(out + base)     = v0;
        *(float4*)(out + base + 4) = v1;
    }
}

// ============================================================
extern "C" void kernel_launch(void* const* d_in, const int* in_sizes, int n_in,
                              void* d_out, int out_size, void* d_ws, size_t ws_size,
                              hipStream_t stream) {
    const float* x    = (const float*)d_in[0];
    const float* w    = (const float*)d_in[1];
    const float* bias = (const float*)d_in[2];
    float* out        = (float*)d_out;

    const size_t Y_OFF    = 2097152;                      // 2 MB aligned
    const size_t Y_BYTES  = (size_t)2 * 16 * YV * 8 * 2;  // 60.2 MB
    const size_t WS_NEED  = Y_OFF + Y_BYTES;

    if (ws_size < WS_NEED) {
        dim3 grid(6*6*3, OCn/128, 2);
        hipLaunchKernelGGL(conv_down3d_fused, grid, dim3(256), 0, stream, x, w, bias, out);
        return;
    }

    unsigned short* wt = (unsigned short*)d_ws;
    unsigned short* yb = (unsigned short*)((char*)d_ws + Y_OFF);

    hipLaunchKernelGGL(w_pack,     dim3(864),        dim3(256), 0, stream, w, wt);
    hipLaunchKernelGGL(fir_y_bf16, dim3(49, 16, 2),  dim3(256), 0, stream, x, yb);
    hipLaunchKernelGGL(conv_mfma,  dim3(216, 2, 2),  dim3(256), 0, stream, wt, yb, bias, out);
}

// Round 5
// 408.702 us; speedup vs baseline: 5.3279x; 1.2270x over previous
//
#include <hip/hip_runtime.h>

// ---------------- problem constants ----------------
#define ICn 128
#define OCn 256
#define ISn 48      // x spatial
#define OSn 24      // out spatial
#define YV  117649  // 49^3
#define K0f (1.0f/11.0f)
#define K1f (3.0f/11.0f)

typedef short  short8  __attribute__((ext_vector_type(8)));
typedef float  floatx4 __attribute__((ext_vector_type(4)));

static __device__ __forceinline__ unsigned short f2bf(float f) {
    union { float f; unsigned u; } v; v.f = f;
    unsigned r = (v.u + 0x7FFF + ((v.u >> 16) & 1)) >> 16;   // RNE
    return (unsigned short)r;
}

// ============================================================
// Kernel 0: repack w (fp32, [256][128][3][3][3]) -> bf16 wt
// wt layout: [g=2][tap=27][ch=4][oc=128][ic=32]
// Coalesced: block b handles ocs b*8..b*8+7 (contiguous 110 KB read),
// transpose routed through LDS, dense contiguous short writes.
// ============================================================
#define WT_ELEMS (2*27*4*128*32)   // 884736
__global__ __launch_bounds__(256) void w_pack(
    const float* __restrict__ w, unsigned short* __restrict__ wt)
{
    __shared__ unsigned short lw[27648];   // [ol=8][ic=128][t=27] bf16
    const int tid = threadIdx.x;
    const int b = blockIdx.x;              // 0..31
    const float* src = w + (size_t)b * 27648;
    for (int i4 = tid; i4 < 6912; i4 += 256) {
        floatx4 v = *(const floatx4*)(src + (size_t)i4*4);
        ushort4 u;
        u.x = f2bf(v.x); u.y = f2bf(v.y); u.z = f2bf(v.z); u.w = f2bf(v.w);
        *(ushort4*)(&lw[i4*4]) = u;
    }
    __syncthreads();
    const int g = b >> 4, bo = b & 15;
    for (int idx = tid; idx < 27648; idx += 256) {
        int i  = idx & 31;
        int ol = (idx >> 5) & 7;
        int rest = idx >> 8;               // t*4 + ch
        int ch = rest & 3, t = rest >> 2;
        unsigned short v = lw[(ol*128 + ch*32 + i)*27 + t];
        wt[(((size_t)(g*27 + t)*4 + ch)*128 + bo*8 + ol)*32 + i] = v;
    }
}

// ============================================================
// Kernel 1: separable FIR  x(2,128,48^3) fp32 -> y bf16
// y layout: yb[n][icg=32][sp=49^3][4 ic]  (8-B dense rows)
// Block: (7z,7y) tile x full 49 x-row, 4 ics. Grid (49, 32, 2).
// z-filter: per-lane g[11] regs (55 LDS reads); y-filter in regs;
// x-filter via cross-lane shuffles (lane = x', OOB lanes carry 0).
// Next-ic x-tile register-prefetched during compute. 2 barriers/ic.
// LDS 42.4 KB -> 3 blocks/CU.
// ============================================================
__global__ __launch_bounds__(256, 3) void fir_y_bf16(
    const float* __restrict__ x, unsigned short* __restrict__ yb)
{
    __shared__ float xs[121*48];             // 23232 B  [(d*11+y)][48]
    __shared__ unsigned short ysl[4*2401];   // 19208 B  [ic][sp(7,7,49)]

    const int tid  = threadIdx.x;
    const int wave = tid >> 6, lane = tid & 63;
    const int tz = blockIdx.x / 7, ty = blockIdx.x % 7;
    const int z0 = tz*7, y0 = ty*7;
    const int icg = blockIdx.y;              // 0..31 (4 ics each)
    const int n   = blockIdx.z;

    const size_t xbase = ((size_t)n*ICn + icg*4) * (size_t)(ISn*ISn*ISn);

    // staging slot geometry (constant per thread)
    floatx4 pf[6];
    int   cc[6], rowoff[6];
    bool  vld[6];
    #pragma unroll
    for (int s = 0; s < 6; ++s) {
        int idx = tid + 256*s;
        int r = idx / 12, c = idx - r*12;
        if (idx < 1452) {
            int d = r/11, yy = r - d*11;
            int gz = z0 - 3 + d, gy = y0 - 3 + yy;
            bool ok = ((unsigned)gz < 48u) && ((unsigned)gy < 48u);
            vld[s] = ok;
            rowoff[s] = r*48 + 4*c;
            cc[s] = ok ? ((gz*ISn + gy)*ISn + 4*c) : 0;
        } else { vld[s] = false; rowoff[s] = 0; cc[s] = 0; }
    }

    // prologue: load ic 0
    {
        const float* xin = x + xbase;
        #pragma unroll
        for (int s = 0; s < 6; ++s) {
            floatx4 v = {0.f,0.f,0.f,0.f};
            if (vld[s]) v = *(const floatx4*)(xin + cc[s]);
            pf[s] = v;
        }
    }

    for (int ic = 0; ic < 4; ++ic) {
        // ---- write staged tile to LDS ----
        #pragma unroll
        for (int s = 0; s < 5; ++s)
            *(floatx4*)(xs + rowoff[s]) = pf[s];
        if (tid < 172) *(floatx4*)(xs + rowoff[5]) = pf[5];
        // ---- issue prefetch for next ic (lands during compute) ----
        if (ic < 3) {
            const float* xin = x + xbase + (size_t)(ic+1)*(ISn*ISn*ISn);
            #pragma unroll
            for (int s = 0; s < 6; ++s) {
                floatx4 v = {0.f,0.f,0.f,0.f};
                if (vld[s]) v = *(const floatx4*)(xin + cc[s]);
                pf[s] = v;
            }
        }
        __syncthreads();

        // ---- compute: z-filter to g[11], y-filter in regs, x via shfl ----
        const int xp = lane;
        for (int zl = wave; zl < 7; zl += 4) {
            float g[11];
            if (xp < 48) {
                const float* col = xs + zl*528 + xp;
                #pragma unroll
                for (int Y = 0; Y < 11; ++Y) {
                    const float* q = col + Y*48;
                    g[Y] = K0f*(q[0] + q[4*528]) + K1f*(q[528] + q[2*528] + q[3*528]);
                }
            } else {
                #pragma unroll
                for (int Y = 0; Y < 11; ++Y) g[Y] = 0.f;
            }
            #pragma unroll
            for (int yl = 0; yl < 7; ++yl) {
                float h = K0f*(g[yl] + g[yl+4]) + K1f*(g[yl+1] + g[yl+2] + g[yl+3]);
                // y[u] = K0*(h[u-3]+h[u+1]) + K1*(h[u-2]+h[u-1]+h[u])
                float hm3 = __shfl(h, (lane + 61) & 63);
                float hm2 = __shfl(h, (lane + 62) & 63);
                float hm1 = __shfl(h, (lane + 63) & 63);
                float hp1 = __shfl(h, (lane + 1) & 63);
                float acc = K0f*(hm3 + hp1) + K1f*(hm2 + hm1 + h);
                if (lane < 49)
                    ysl[ic*2401 + (zl*7 + yl)*49 + lane] = f2bf(acc);
            }
        }
        __syncthreads();
    }

    // ---- flush: pack 4 ics -> uint2, dense contiguous stores ----
    const size_t ybase4 = ((size_t)(n*32 + icg)) * YV * 4;   // ushort units
    for (int idx = tid; idx < 2401; idx += 256) {
        unsigned u0 = (unsigned)ysl[idx]        | ((unsigned)ysl[2401 + idx] << 16);
        unsigned u1 = (unsigned)ysl[4802 + idx] | ((unsigned)ysl[7203 + idx] << 16);
        int zl = idx / 343; int rem = idx - zl*343;
        int yl = rem / 49;  int u = rem - yl*49;
        size_t g_sp = (size_t)(z0+zl)*2401 + (size_t)(y0+yl)*49 + u;
        *(uint2*)(yb + ybase4 + g_sp*4) = make_uint2(u0, u1);
    }
}

// ============================================================
// Kernel 2: conv via MFMA.  out(2,256,24^3) fp32
// block: 128 oc x 64 pts (4x4x4); 4 waves = 2(oc) x 2(pts)
// B in LDS [icq=4][729 sp][8]: one aligned ds_read_b128/frag.
// A-fragments prefetched one tap ahead (breaks serial vmem waits).
// ============================================================
__global__ __launch_bounds__(256, 3) void conv_mfma(
    const unsigned short* __restrict__ wt,
    const unsigned short* __restrict__ yb,
    const float* __restrict__ bias,
    float* __restrict__ out)
{
    __shared__ unsigned short ys3[4*729*8];   // 46656 B

    const int tid  = threadIdx.x;
    const int wav  = tid >> 6;
    const int lane = tid & 63;
    const int quad = lane >> 4;
    const int m    = lane & 15;
    const int wm   = wav & 1;       // oc half
    const int wn   = wav >> 1;      // pt half (od pairs)

    int bx = blockIdx.x;
    const int td = bx / 36; int r0 = bx - td*36;
    const int th = r0 / 6;  const int tw = r0 - th*6;
    const int g  = blockIdx.y;      // ocg
    const int n  = blockIdx.z;
    const int oc0 = g * 128;

    const int oh2 = (m >> 2) * 2;
    const int ow2 = (m & 3) * 2;

    floatx4 acc[4][2];
    #pragma unroll
    for (int mi = 0; mi < 4; ++mi) {
        floatx4 bv = *(const floatx4*)(bias + oc0 + wm*64 + mi*16 + quad*4);
        acc[mi][0] = bv; acc[mi][1] = bv;
    }

    const short8* wt8 = (const short8*)wt;
    const int gz0 = 8*td, gy0 = 8*th, gx0 = 8*tw;

    for (int chk = 0; chk < 4; ++chk) {
        if (chk) __syncthreads();
        // ---- stage y chunk: 4 icq regions x 729 sp from [sp][4ic] y ----
        for (int idx = tid; idx < 2916; idx += 256) {
            int icq = idx / 729, sp = idx - icq*729;
            int zs = sp / 81; int r = sp - zs*81; int ysv = r / 9; int xsv = r - ysv*9;
            size_t g_sp = (size_t)(gz0 + zs)*2401 + (size_t)(gy0 + ysv)*49 + (gx0 + xsv);
            const unsigned short* s0 =
                yb + ((size_t)(n*32 + chk*8 + 2*icq))     * YV * 4 + g_sp*4;
            const unsigned short* s1 =
                yb + ((size_t)(n*32 + chk*8 + 2*icq + 1)) * YV * 4 + g_sp*4;
            uint2 va = *(const uint2*)s0;
            uint2 vb = *(const uint2*)s1;
            *(uint4*)(&ys3[((size_t)icq*729 + sp)*8]) = make_uint4(va.x, va.y, vb.x, vb.y);
        }
        __syncthreads();

        // ---- compute: 27 taps, K=32 mfma, A prefetched 1 tap ahead ----
        const int A0 = (g*108 + chk)*512 + (wm*64 + m)*4 + quad;  // short8 units
        short8 Acur[4], Anxt[4];
        #pragma unroll
        for (int mi = 0; mi < 4; ++mi) Acur[mi] = wt8[A0 + mi*64];
        #pragma unroll
        for (int t = 0; t < 27; ++t) {
            if (t < 26) {
                #pragma unroll
                for (int mi = 0; mi < 4; ++mi)
                    Anxt[mi] = wt8[A0 + (t+1)*2048 + mi*64];
            }
            const int a  = t / 9;
            const int b2 = (t / 3) % 3;
            const int c  = t % 3;
            short8 B[2];
            #pragma unroll
            for (int ni = 0; ni < 2; ++ni) {
                const int zs = 2*(wn*2 + ni) + a;
                const int sp = (zs*9 + oh2 + b2)*9 + ow2 + c;
                B[ni] = *(const short8*)(&ys3[((size_t)quad*729 + sp)*8]);
            }
            #pragma unroll
            for (int mi = 0; mi < 4; ++mi)
                #pragma unroll
                for (int ni = 0; ni < 2; ++ni)
                    acc[mi][ni] = __builtin_amdgcn_mfma_f32_16x16x32_bf16(
                        Acur[mi], B[ni], acc[mi][ni], 0, 0, 0);
            #pragma unroll
            for (int mi = 0; mi < 4; ++mi) Acur[mi] = Anxt[mi];
        }
    }

    // ---- epilogue: D row = oc (quad*4+r), col = pt (lane&15) ----
    const int ohl = m >> 2, owl = m & 3;
    #pragma unroll
    for (int mi = 0; mi < 4; ++mi) {
        #pragma unroll
        for (int ni = 0; ni < 2; ++ni) {
            const int odl = wn*2 + ni;
            #pragma unroll
            for (int r = 0; r < 4; ++r) {
                const int oc = oc0 + wm*64 + mi*16 + quad*4 + r;
                size_t addr = ((((size_t)n*OCn + oc)*OSn + td*4 + odl)*OSn + th*4 + ohl)*OSn
                              + tw*4 + owl;
                out[addr] = acc[mi][ni][r];
            }
        }
    }
}

// ============================================================
// Fallback (round-1 fused fp32 kernel) if ws too small
// ============================================================
#define TD 4
#define TH 4
#define TW 8
#define XD 13
#define XH 13
#define XW 21
#define YW 17
#define YD 9
#define YH 9
#define XS_LEN (XD*XH*XW)
#define AS_OFF XS_LEN
#define AS_LEN (XD*XH*YW)
#define BS_OFF (AS_OFF + AS_LEN)
#define BS_LEN (XD*YH*YW)
#define WS_OFF 8412
#define WROW 136
#define LDS_TOT (WS_OFF + 27*WROW)

__global__ __launch_bounds__(256) void conv_down3d_fused(
    const float* __restrict__ x, const float* __restrict__ w,
    const float* __restrict__ bias, float* __restrict__ out)
{
    __shared__ float lds[LDS_TOT];
    float* xs = lds;
    float* as = lds + AS_OFF;
    float* bs = lds + BS_OFF;
    float* ws = lds + WS_OFF;
    float* ys = lds;

    const int tid = threadIdx.x;
    int s = blockIdx.x;
    const int tw = s % 3; s /= 3;
    const int th = s % 6; const int td = s / 6;
    const int od0 = td*TD, oh0 = th*TH, ow0 = tw*TW;
    const int oc0 = blockIdx.y * 128;
    const int n   = blockIdx.z;
    const int og = tid >> 4;
    const int pg = tid & 15;
    const int od = pg >> 2;
    const int oh = pg & 3;

    float acc[8][8];
    #pragma unroll
    for (int o = 0; o < 8; ++o) {
        const float bv = bias[oc0 + og*8 + o];
        #pragma unroll
        for (int p = 0; p < 8; ++p) acc[o][p] = bv;
    }

    const int x0d = 2*od0 - 3, x0h = 2*oh0 - 3, x0w = 2*ow0 - 3;
    const float* xn = x + (size_t)n * ICn * (ISn*ISn*ISn);
    const float* wg = w + (size_t)oc0 * (ICn*27);

    for (int ic = 0; ic < ICn; ++ic) {
        const float* xin = xn + (size_t)ic * (ISn*ISn*ISn);
        for (int idx = tid; idx < XS_LEN; idx += 256) {
            int lz = idx / (XH*XW);
            int r  = idx - lz*(XH*XW);
            int ly = r / XW;
            int lx = r - ly*XW;
            int gz = x0d + lz, gy = x0h + ly, gx = x0w + lx;
            float v = 0.0f;
            if ((unsigned)gz < (unsigned)ISn && (unsigned)gy < (unsigned)ISn &&
                (unsigned)gx < (unsigned)ISn)
                v = xin[((size_t)gz*ISn + gy)*ISn + gx];
            xs[idx] = v;
        }
        for (int idx = tid; idx < 27*128; idx += 256) {
            int oc  = idx / 27;
            int tap = idx - oc*27;
            ws[tap*WROW + oc] = wg[(size_t)oc*(ICn*27) + ic*27 + tap];
        }
        __syncthreads();
        for (int idx = tid; idx < AS_LEN; idx += 256) {
            int z = idx / (XH*YW);
            int r = idx - z*(XH*YW);
            int yy = r / YW;
            int u  = r - yy*YW;
            const float* p0 = &xs[(z*XH + yy)*XW + u];
            as[idx] = K0f*(p0[0] + p0[4]) + K1f*(p0[1] + p0[2] + p0[3]);
        }
        __syncthreads();
        for (int idx = tid; idx < BS_LEN; idx += 256) {
            int z = idx / (YH*YW);
            int r = idx - z*(YH*YW);
            int v = r / YW;
            int u = r - v*YW;
            const float* p0 = &as[(z*XH + v)*YW + u];
            bs[idx] = K0f*(p0[0] + p0[4*YW]) + K1f*(p0[YW] + p0[2*YW] + p0[3*YW]);
        }
        __syncthreads();
        for (int idx = tid; idx < YD*YH*YW; idx += 256) {
            int t = idx / (YH*YW);
            int r = idx - t*(YH*YW);
            int v = r / YW;
            int u = r - v*YW;
            const float* p0 = &bs[(t*YH + v)*YW + u];
            ys[idx] = K0f*(p0[0] + p0[4*(YH*YW)]) +
                      K1f*(p0[YH*YW] + p0[2*(YH*YW)] + p0[3*(YH*YW)]);
        }
        __syncthreads();
        #pragma unroll
        for (int a = 0; a < 3; ++a) {
            #pragma unroll
            for (int b = 0; b < 3; ++b) {
                const float* yrow = &ys[((2*od + a)*YH + (2*oh + b))*YW];
                #pragma unroll
                for (int c = 0; c < 3; ++c) {
                    float yv[8];
                    #pragma unroll
                    for (int p = 0; p < 8; ++p) yv[p] = yrow[2*p + c];
                    const float* wrow = &ws[(a*9 + b*3 + c)*WROW + og*8];
                    float wv[8];
                    #pragma unroll
                    for (int o = 0; o < 8; ++o) wv[o] = wrow[o];
                    #pragma unroll
                    for (int o = 0; o < 8; ++o)
                        #pragma unroll
                        for (int p = 0; p < 8; ++p)
                            acc[o][p] += wv[o] * yv[p];
                }
            }
        }
        __syncthreads();
    }
    #pragma unroll
    for (int o = 0; o < 8; ++o) {
        size_t base = ((((size_t)n*OCn + oc0 + og*8 + o)*OSn + (od0+od))*OSn + (oh0+oh))*OSn + ow0;
        float4 v0 = make_float4(acc[o][0], acc[o][1], acc[o][2], acc[o][3]);
        float4 v1 = make_float4(acc[o][4], acc[o][5], acc[o][6], acc[o][7]);
        *(float4*)(out + base)     = v0;
        *(float4*)(out + base + 4) = v1;
    }
}

// ============================================================
extern "C" void kernel_launch(void* const* d_in, const int* in_sizes, int n_in,
                              void* d_out, int out_size, void* d_ws, size_t ws_size,
                              hipStream_t stream) {
    const float* x    = (const float*)d_in[0];
    const float* w    = (const float*)d_in[1];
    const float* bias = (const float*)d_in[2];
    float* out        = (float*)d_out;

    const size_t Y_OFF    = 2097152;                      // 2 MB aligned
    const size_t Y_BYTES  = (size_t)2 * 32 * YV * 4 * 2;  // 60.2 MB
    const size_t WS_NEED  = Y_OFF + Y_BYTES;

    if (ws_size < WS_NEED) {
        dim3 grid(6*6*3, OCn/128, 2);
        hipLaunchKernelGGL(conv_down3d_fused, grid, dim3(256), 0, stream, x, w, bias, out);
        return;
    }

    unsigned short* wt = (unsigned short*)d_ws;
    unsigned short* yb = (unsigned short*)((char*)d_ws + Y_OFF);

    hipLaunchKernelGGL(w_pack,     dim3(32),         dim3(256), 0, stream, w, wt);
    hipLaunchKernelGGL(fir_y_bf16, dim3(49, 32, 2),  dim3(256), 0, stream, x, yb);
    hipLaunchKernelGGL(conv_mfma,  dim3(216, 2, 2),  dim3(256), 0, stream, wt, yb, bias, out);
}